// Round 6
// baseline (402.243 us; speedup 1.0000x reference)
//
#include <hip/hip_runtime.h>

#define IN_F   2048
#define OUT_F  2048
#define GDIM   8
#define BATCH  8192
#define KDIM   4096   // concat K = 2*2048
#define GRID_TOTAL_INV (1.0f / 33554432.0f)  // 1/(2048*2048*8)

#define BK     64
#define NKT    (KDIM / BK)   // 64 K-tiles
#define BUFSZ  65536         // per buffer: A 32K (2 kk-regions) + B 32K
#define BOFF   32768         // B offset within buffer
#define REG    16384         // one kk-region: 256 rows x 32 k x 2B

typedef __bf16 bf16x8 __attribute__((ext_vector_type(8)));
typedef float  f32x4  __attribute__((ext_vector_type(4)));
typedef unsigned short u16x8 __attribute__((ext_vector_type(8)));

__device__ __forceinline__ unsigned short f2bf(float f) {
  union { float f; unsigned int u; } v; v.f = f;
  unsigned int r = v.u + 0x7fffu + ((v.u >> 16) & 1u);  // RNE
  return (unsigned short)(r >> 16);
}

__device__ __forceinline__ void gload_lds16(const void* g, void* l) {
  __builtin_amdgcn_global_load_lds(
      (const __attribute__((address_space(1))) void*)g,
      (__attribute__((address_space(3))) void*)l, 16, 0, 0);
}

// ---------------- prep 1: base_weight (OUT,IN) f32 -> Bt[o][k<2048] bf16 ----
__global__ __launch_bounds__(256) void prep_bw(const float* __restrict__ bw,
                                               unsigned short* __restrict__ Bt,
                                               float* __restrict__ sum_ptr) {
  if (blockIdx.x == 0 && threadIdx.x == 0) *sum_ptr = 0.0f;  // zero mean-acc
  size_t i8 = ((size_t)blockIdx.x * 256 + threadIdx.x) * 8;
  const float4* p = reinterpret_cast<const float4*>(bw + i8);
  float4 a = p[0], b = p[1];
  u16x8 v;
  v[0] = f2bf(a.x); v[1] = f2bf(a.y); v[2] = f2bf(a.z); v[3] = f2bf(a.w);
  v[4] = f2bf(b.x); v[5] = f2bf(b.y); v[6] = f2bf(b.z); v[7] = f2bf(b.w);
  size_t o = i8 >> 11;       // row (out)
  size_t k = i8 & 2047;      // col (in)
  *reinterpret_cast<u16x8*>(Bt + o * KDIM + k) = v;
}

// ---------------- prep 2: grid (IN,OUT,8) f32 -> Bt[o][2048+i] = sum_g, + mean
__global__ __launch_bounds__(256) void prep_grid(const float* __restrict__ grid,
                                                 unsigned short* __restrict__ Bt,
                                                 float* __restrict__ sum_ptr) {
  __shared__ float tile[32][33];
  __shared__ float wsum[4];
  int bi = blockIdx.x >> 6;   // i-tile (64 tiles of 32)
  int bo = blockIdx.x & 63;   // o-tile
  int i0 = bi << 5, o0 = bo << 5;
  int t = threadIdx.x;
  float local = 0.f;
#pragma unroll
  for (int p = 0; p < 4; ++p) {
    int li = t + 256 * p;
    int il = li >> 5, ol = li & 31;
    const float4* g4 = reinterpret_cast<const float4*>(
        grid + ((size_t)(i0 + il) * OUT_F + (size_t)(o0 + ol)) * GDIM);
    float4 a = g4[0], b = g4[1];
    float s = ((a.x + a.y) + (a.z + a.w)) + ((b.x + b.y) + (b.z + b.w));
    tile[il][ol] = s;
    local += s;
  }
#pragma unroll
  for (int off = 32; off >= 1; off >>= 1) local += __shfl_down(local, off, 64);
  int lane = t & 63, w = t >> 6;
  if (lane == 0) wsum[w] = local;
  __syncthreads();
#pragma unroll
  for (int p = 0; p < 4; ++p) {
    int li = t + 256 * p;
    int ol = li >> 5, il = li & 31;   // transposed: consecutive t -> consecutive i
    Bt[(size_t)(o0 + ol) * KDIM + IN_F + (i0 + il)] = f2bf(tile[il][ol]);
  }
  if (t == 0) atomicAdd(sum_ptr, (wsum[0] + wsum[1]) + (wsum[2] + wsum[3]));
}

// ---------------- prep 3: A = [bf16(x) | bf16(exp(-(x-m)^2))] ----------------
__global__ __launch_bounds__(256) void prep_A(const float* __restrict__ x,
                                              const float* __restrict__ sum_ptr,
                                              unsigned short* __restrict__ Abuf) {
  float m = *sum_ptr * GRID_TOTAL_INV;
  size_t i8 = ((size_t)blockIdx.x * 256 + threadIdx.x) * 8;
  const float4* p = reinterpret_cast<const float4*>(x + i8);
  float4 a = p[0], b = p[1];
  float xs[8] = {a.x, a.y, a.z, a.w, b.x, b.y, b.z, b.w};
  u16x8 xv, bv;
#pragma unroll
  for (int j = 0; j < 8; ++j) {
    xv[j] = f2bf(xs[j]);
    float d = xs[j] - m;
    bv[j] = f2bf(__expf(-d * d));
  }
  size_t bi = i8 >> 11;
  size_t k  = i8 & 2047;
  *reinterpret_cast<u16x8*>(Abuf + bi * KDIM + k) = xv;
  *reinterpret_cast<u16x8*>(Abuf + bi * KDIM + IN_F + k) = bv;
}

// ---------------- GEMM: C(8192x2048) = A(8192x4096) * Bt(2048x4096)^T --------
// Full m201 cadence: 4 phases/K-tile, each phase =
//   { ds_read subtile (4 or 8 b128, PRE-barrier: latency hides under sync)
//     | stage 1 region (2 gload_lds) | [vmcnt(4) at P1,P3]
//     -> s_barrier -> lgkm0 -> setprio1 -> 16 MFMA -> setprio0 -> s_barrier }
// vmcnt invariant: entering tile kt, outstanding = {A-kk1,B-kk1}(kt).
//   P0 +Akk0(kt+1)=6; P1 +Bkk0=8, vmcnt(4) retires {Akk1,Bkk1}(kt) before P2
//   reads them; P2 +Akk1=6; P3 +Bkk1=8, vmcnt(4) retires {Akk0,Bkk0}(kt+1)
//   before next-P0 reads them. Never below 4 in flight (T4).
// Write-hazard: stage into buf[1-cur] region R at phase p: all reads of R
//   (tile kt-1, same buffer) were lgkm-drained before kt-1/P3's trailing
//   barrier, which every wave crossed before any wave enters kt/P0. Safe.
// WAR: separate reg buffers afA/afB/bfA/bfB so a phase's ds_read never
//   overwrites the regs the previous phase's MFMA is consuming.
// Swizzle (rule 21, both-sides): chunk c at c^((row>>2)&3) via pre-swizzled
//   global source; ds_read same XOR. Residual 1.26e7 conflicts = gload_lds
//   write bursts (structure-invariant, measured r2/r3/r5).
__global__ __launch_bounds__(512, 2) void gemm_kernel(
    const unsigned short* __restrict__ A,
    const unsigned short* __restrict__ B,
    float* __restrict__ C) {
  __shared__ __align__(16) char lds[2 * BUFSZ];  // 128 KiB
  const int t    = threadIdx.x;
  const int lane = t & 63;
  const int wid  = t >> 6;        // 0..7
  const int wm   = wid >> 2;      // 0..1
  const int wn   = wid & 3;       // 0..3
  // XCD-clustered mapping: xcd = bx&7 gets bm in [xcd*4, xcd*4+4) x all 8 bn.
  const int bx = blockIdx.x;
  const int bm = ((bx & 7) << 2) | ((bx >> 3) & 3);  // 0..31
  const int bn = bx >> 5;                            // 0..7

  f32x4 acc[8][4] = {};
  bf16x8 afA[4], afB[4], bfA[4], bfB[4];

  // staging: thread t covers region rows (t>>2) and 128+(t>>2), chunk (t&3).
  // source chunk pre-swizzled: cs = (t&3) ^ ((row>>2)&3) = (t&3) ^ ((t>>4)&3).
  const int cs = (t & 3) ^ ((t >> 4) & 3);
  const unsigned short* aStage = A + ((size_t)(bm * 256 + (t >> 2)) * KDIM) + cs * 8;
  const unsigned short* bStage = B + ((size_t)(bn * 256 + (t >> 2)) * KDIM) + cs * 8;
  const int dOff = t * 16;

  // ds_read: global chunk (lane>>4) lives at LDS chunk (lane>>4)^((row>>2)&3);
  // (row>>2)&3 == (lane>>2)&3 for all frag rows (row = 16-aligned + (lane&15)).
  const int sc  = (lane >> 4) ^ ((lane >> 2) & 3);
  const int aRd = (wm * 128 + (lane & 15)) * 64 + sc * 16;
  const int bRd = (wn * 64  + (lane & 15)) * 64 + sc * 16;

#define STAGE_R(wb, kt, opOff, kk, src)                                        \
  gload_lds16((src) + (size_t)(kt) * BK + (kk) * 32,                           \
              (wb) + (opOff) + (kk) * REG + dOff);                             \
  gload_lds16((src) + 128 * KDIM + (size_t)(kt) * BK + (kk) * 32,              \
              (wb) + (opOff) + (kk) * REG + 8192 + dOff);

#define PH_READ_A(dst, rb, kk, mb)                                             \
  _Pragma("unroll")                                                            \
  for (int i_ = 0; i_ < 4; ++i_)                                               \
    dst[i_] = *reinterpret_cast<const bf16x8*>(                                \
        (rb) + (kk) * REG + aRd + ((mb) + i_) * 1024);

#define PH_READ_B(dst, rb, kk)                                                 \
  _Pragma("unroll")                                                            \
  for (int n_ = 0; n_ < 4; ++n_)                                               \
    dst[n_] = *reinterpret_cast<const bf16x8*>(                                \
        (rb) + BOFF + (kk) * REG + bRd + n_ * 1024);

#define SBAR0 __builtin_amdgcn_sched_barrier(0);

#define LGKM0                                                                  \
  asm volatile("s_waitcnt lgkmcnt(0)" ::: "memory");                           \
  __builtin_amdgcn_sched_barrier(0);

#define MFMA16(a_, b_, mb)                                                     \
  __builtin_amdgcn_s_setprio(1);                                               \
  _Pragma("unroll")                                                            \
  for (int i_ = 0; i_ < 4; ++i_)                                               \
    _Pragma("unroll")                                                          \
    for (int n_ = 0; n_ < 4; ++n_)                                             \
      acc[(mb) + i_][n_] = __builtin_amdgcn_mfma_f32_16x16x32_bf16(            \
          a_[i_], b_[n_], acc[(mb) + i_][n_], 0, 0, 0);                        \
  __builtin_amdgcn_s_setprio(0);

#define VMCNT(n) asm volatile("s_waitcnt vmcnt(" #n ")" ::: "memory");

#define BAR __builtin_amdgcn_s_barrier();

  // prologue: stage tile 0 in read order; retire {Akk0,Bkk0} before P0 reads.
  STAGE_R(lds, 0, 0,    0, aStage);
  STAGE_R(lds, 0, BOFF, 0, bStage);
  STAGE_R(lds, 0, 0,    1, aStage);
  STAGE_R(lds, 0, BOFF, 1, bStage);
  VMCNT(4);
  BAR;

  for (int kt = 0; kt < NKT - 1; ++kt) {
    const char* rb = lds + (kt & 1) * BUFSZ;
    char* wb = lds + ((kt + 1) & 1) * BUFSZ;
    // P0
    PH_READ_A(afA, rb, 0, 0); PH_READ_B(bfA, rb, 0);
    STAGE_R(wb, kt + 1, 0, 0, aStage);        // A-kk0(kt+1)
    SBAR0; BAR;
    LGKM0; MFMA16(afA, bfA, 0);
    BAR;
    // P1
    PH_READ_A(afB, rb, 0, 4);
    STAGE_R(wb, kt + 1, BOFF, 0, bStage);     // B-kk0(kt+1)
    VMCNT(4); SBAR0; BAR;
    LGKM0; MFMA16(afB, bfA, 4);
    BAR;
    // P2
    PH_READ_A(afA, rb, 1, 0); PH_READ_B(bfB, rb, 1);
    STAGE_R(wb, kt + 1, 0, 1, aStage);        // A-kk1(kt+1)
    SBAR0; BAR;
    LGKM0; MFMA16(afA, bfB, 0);
    BAR;
    // P3
    PH_READ_A(afB, rb, 1, 4);
    STAGE_R(wb, kt + 1, BOFF, 1, bStage);     // B-kk1(kt+1)
    VMCNT(4); SBAR0; BAR;
    LGKM0; MFMA16(afB, bfB, 4);
    BAR;
  }
  {  // tail tile NKT-1 (odd -> buffer 1), no staging
    const char* rb = lds + ((NKT - 1) & 1) * BUFSZ;
    // P0
    PH_READ_A(afA, rb, 0, 0); PH_READ_B(bfA, rb, 0);
    SBAR0; BAR; LGKM0; MFMA16(afA, bfA, 0); BAR;
    // P1
    PH_READ_A(afB, rb, 0, 4);
    VMCNT(0); SBAR0; BAR; LGKM0; MFMA16(afB, bfA, 4); BAR;
    // P2
    PH_READ_A(afA, rb, 1, 0); PH_READ_B(bfB, rb, 1);
    SBAR0; BAR; LGKM0; MFMA16(afA, bfB, 0); BAR;
    // P3
    PH_READ_A(afB, rb, 1, 4);
    LGKM0; MFMA16(afB, bfB, 4);
  }

  // epilogue: C/D layout col=lane&15, row=(lane>>4)*4+reg  [m89/m91 verified]
  const int rg = lane >> 4, cc = lane & 15;
  const size_t crow0 = (size_t)bm * 256 + wm * 128;
  const size_t ccol0 = (size_t)bn * 256 + wn * 64;
#pragma unroll
  for (int m = 0; m < 8; ++m)
#pragma unroll
    for (int n = 0; n < 4; ++n)
#pragma unroll
      for (int rr = 0; rr < 4; ++rr) {
        size_t row = crow0 + (size_t)m * 16 + rg * 4 + rr;
        size_t col = ccol0 + (size_t)n * 16 + cc;
        C[row * OUT_F + col] = acc[m][n][rr];
      }
}

extern "C" void kernel_launch(void* const* d_in, const int* in_sizes, int n_in,
                              void* d_out, int out_size, void* d_ws, size_t ws_size,
                              hipStream_t stream) {
  const float* x    = (const float*)d_in[0];
  const float* bw   = (const float*)d_in[1];
  const float* grid = (const float*)d_in[2];
  float* out = (float*)d_out;

  // workspace: A (8192x4096 bf16, 64MB) | Bt (2048x4096 bf16, 16MB) | sum (4B)
  unsigned short* Abuf = (unsigned short*)d_ws;
  unsigned short* Bt   = Abuf + (size_t)BATCH * KDIM;
  float* sum_ptr = (float*)(Bt + (size_t)OUT_F * KDIM);

  prep_bw  <<<(OUT_F * IN_F / 8) / 256, 256, 0, stream>>>(bw, Bt, sum_ptr);
  prep_grid<<<64 * 64,                  256, 0, stream>>>(grid, Bt, sum_ptr);
  prep_A   <<<(BATCH * IN_F / 8) / 256, 256, 0, stream>>>(x, sum_ptr, Abuf);
  gemm_kernel<<<256, 512, 0, stream>>>(Abuf, Bt, out);
}